// Round 1
// baseline (1948.660 us; speedup 1.0000x reference)
//
#include <hip/hip_runtime.h>
#include <math.h>

#define LSEQ   4096
#define DMODEL 1024
#define NH     16
#define DHEAD  64

// ---------------------------------------------------------------------------
// NT GEMM: C[i][j] = sum_k A[i][k] * B[j][k], A: M x K, B: N x K, row-major.
// M = LSEQ, N = K = DMODEL. Tile 64x64, BK=16, 256 threads, 4x4 per thread.
// MODE 0: plain row-major write (final output projection)
// MODE 1: RoPE epilogue -> head layout out[h][i][t] (Q and K)
// MODE 2: copy -> head layout out[h][i][d] (V)
// ---------------------------------------------------------------------------
template<int MODE>
__global__ __launch_bounds__(256)
void gemm_nt(const float* __restrict__ A, const float* __restrict__ B,
             float* __restrict__ C) {
  __shared__ float As[64][17];   // +1 pad: inner reads are 2-way at worst (free)
  __shared__ float Bs[64][17];
  const int i0  = blockIdx.x * 64;
  const int j0  = blockIdx.y * 64;
  const int tid = threadIdx.x;
  const int tx  = tid & 15, ty = tid >> 4;
  const int lr  = tid >> 2;          // 0..63  (load row)
  const int lk  = (tid & 3) << 2;    // 0,4,8,12 (load col, float4)

  float acc[4][4] = {};

  for (int k0 = 0; k0 < DMODEL; k0 += 16) {
    const float4 av = *(const float4*)(A + (size_t)(i0 + lr) * DMODEL + k0 + lk);
    const float4 bv = *(const float4*)(B + (size_t)(j0 + lr) * DMODEL + k0 + lk);
    As[lr][lk + 0] = av.x; As[lr][lk + 1] = av.y;
    As[lr][lk + 2] = av.z; As[lr][lk + 3] = av.w;
    Bs[lr][lk + 0] = bv.x; Bs[lr][lk + 1] = bv.y;
    Bs[lr][lk + 2] = bv.z; Bs[lr][lk + 3] = bv.w;
    __syncthreads();
#pragma unroll
    for (int k = 0; k < 16; ++k) {
      float a[4], b[4];
#pragma unroll
      for (int r = 0; r < 4; ++r) a[r] = As[4 * ty + r][k];
#pragma unroll
      for (int c = 0; c < 4; ++c) b[c] = Bs[4 * tx + c][k];
#pragma unroll
      for (int r = 0; r < 4; ++r)
#pragma unroll
        for (int c = 0; c < 4; ++c)
          acc[r][c] = fmaf(a[r], b[c], acc[r][c]);
    }
    __syncthreads();
  }

  if (MODE == 0) {
#pragma unroll
    for (int r = 0; r < 4; ++r) {
      const int i = i0 + 4 * ty + r;
#pragma unroll
      for (int c = 0; c < 4; ++c)
        C[(size_t)i * DMODEL + j0 + 4 * tx + c] = acc[r][c];
    }
  } else if (MODE == 2) {
    const int h = j0 >> 6;
#pragma unroll
    for (int r = 0; r < 4; ++r) {
      const int i = i0 + 4 * ty + r;
#pragma unroll
      for (int c = 0; c < 4; ++c)
        C[((size_t)h * LSEQ + i) * DHEAD + (4 * tx + c)] = acc[r][c];
    }
  } else {
    // RoPE: columns within head: pair (2t, 2t+1) -> outputs at t and t+32.
    // Thread owns cols 4tx..4tx+3 of a 64-wide head block => t = 2tx, 2tx+1.
    const int h = j0 >> 6;
#pragma unroll
    for (int p = 0; p < 2; ++p) {
      const int t = 2 * tx + p;
      // inv_freq = 10000^(-t/32); double for table math (epilogue-only cost)
      const double invf = exp((double)t * -0.28782313662425572);  // -ln(10000)/32
#pragma unroll
      for (int r = 0; r < 4; ++r) {
        const int i = i0 + 4 * ty + r;
        const float ang = (float)((double)i * invf);
        const float cs = cosf(ang), sn = sinf(ang);
        const float x1 = acc[r][2 * p], x2 = acc[r][2 * p + 1];
        float* base = C + ((size_t)h * LSEQ + i) * DHEAD;
        base[t]      = x1 * cs - x2 * sn;
        base[t + 32] = x1 * sn + x2 * cs;
      }
    }
  }
}

// ---------------------------------------------------------------------------
// Causal flash attention. One block = (head h, 64 q-rows). 256 threads.
// K/V tiles of 32 rows; online softmax state per q-row in LDS.
// Thread grid 16(ty) x 16(tx): S tile rows 4ty+r (r<4), cols 2tx+c (c<2);
// PV output dims 4tx+dd (dd<4).
// ---------------------------------------------------------------------------
__global__ __launch_bounds__(256)
void attn_flash(const float* __restrict__ Qh, const float* __restrict__ Kh,
                const float* __restrict__ Vh, float* __restrict__ Om) {
  const int h  = blockIdx.x;
  const int qb = blockIdx.y;
  __shared__ float Qs[64][65];   // pad 65: conflict-free row passes
  __shared__ float Ks[32][65];
  __shared__ float Vs[32][64];
  __shared__ float Ss[64][33];   // pad 33: row pass (tid+j)%32 conflict-free
  __shared__ float mS[64], lS[64], aS[64];

  const int tid = threadIdx.x;
  const int tx  = tid & 15, ty = tid >> 4;
  const float scale = 0.125f;  // 1/sqrt(64)

  // load Q tile (64 x 64 floats = 1024 float4)
  const float* Qbase = Qh + ((size_t)h * LSEQ + (size_t)qb * 64) * DHEAD;
#pragma unroll
  for (int it = 0; it < 4; ++it) {
    const int e  = tid + 256 * it;
    const int r  = e >> 4;
    const int d4 = (e & 15) << 2;
    const float4 qv = *(const float4*)(Qbase + r * DHEAD + d4);
    Qs[r][d4 + 0] = qv.x; Qs[r][d4 + 1] = qv.y;
    Qs[r][d4 + 2] = qv.z; Qs[r][d4 + 3] = qv.w;
  }
  if (tid < 64) { mS[tid] = -INFINITY; lS[tid] = 0.0f; }

  float O[4][4] = {};
  const int kb_max = 2 * qb + 1;  // last 32-key tile touching the diagonal

  for (int kb = 0; kb <= kb_max; ++kb) {
    __syncthreads();  // previous PV done reading Ss/Vs (also covers Q stores)
    const float* Kbase = Kh + ((size_t)h * LSEQ + (size_t)kb * 32) * DHEAD;
    const float* Vbase = Vh + ((size_t)h * LSEQ + (size_t)kb * 32) * DHEAD;
#pragma unroll
    for (int it = 0; it < 2; ++it) {
      const int e  = tid + 256 * it;
      const int r  = e >> 4;
      const int d4 = (e & 15) << 2;
      const float4 kv = *(const float4*)(Kbase + r * DHEAD + d4);
      Ks[r][d4 + 0] = kv.x; Ks[r][d4 + 1] = kv.y;
      Ks[r][d4 + 2] = kv.z; Ks[r][d4 + 3] = kv.w;
      const float4 vv = *(const float4*)(Vbase + r * DHEAD + d4);
      Vs[r][d4 + 0] = vv.x; Vs[r][d4 + 1] = vv.y;
      Vs[r][d4 + 2] = vv.z; Vs[r][d4 + 3] = vv.w;
    }
    __syncthreads();

    // S = scale * Q K^T with causal mask
    float s[4][2] = {};
#pragma unroll 8
    for (int k = 0; k < 64; ++k) {
      float a[4], b[2];
#pragma unroll
      for (int r = 0; r < 4; ++r) a[r] = Qs[4 * ty + r][k];
      b[0] = Ks[2 * tx + 0][k];
      b[1] = Ks[2 * tx + 1][k];
#pragma unroll
      for (int r = 0; r < 4; ++r) {
        s[r][0] = fmaf(a[r], b[0], s[r][0]);
        s[r][1] = fmaf(a[r], b[1], s[r][1]);
      }
    }
    const int qi0 = qb * 64 + 4 * ty;
    const int kj0 = kb * 32 + 2 * tx;
#pragma unroll
    for (int r = 0; r < 4; ++r)
#pragma unroll
      for (int c = 0; c < 2; ++c)
        Ss[4 * ty + r][2 * tx + c] =
            (kj0 + c <= qi0 + r) ? s[r][c] * scale : -INFINITY;
    __syncthreads();

    // online softmax per row (thread tid owns row tid; rows 0..63)
    if (tid < 64) {
      const float m_old = mS[tid];
      float mx = m_old;
#pragma unroll 8
      for (int j = 0; j < 32; ++j) mx = fmaxf(mx, Ss[tid][j]);
      const float alpha = __expf(m_old - mx);  // exp(-inf)=0 at first tile
      float sum = 0.0f;
#pragma unroll 8
      for (int j = 0; j < 32; ++j) {
        const float p = __expf(Ss[tid][j] - mx);
        Ss[tid][j] = p;
        sum += p;
      }
      lS[tid] = lS[tid] * alpha + sum;
      mS[tid] = mx;
      aS[tid] = alpha;
    }
    __syncthreads();

    // rescale accumulator, then O += P * V
    float al[4];
#pragma unroll
    for (int r = 0; r < 4; ++r) al[r] = aS[4 * ty + r];
#pragma unroll
    for (int r = 0; r < 4; ++r)
#pragma unroll
      for (int dd = 0; dd < 4; ++dd) O[r][dd] *= al[r];
#pragma unroll 8
    for (int j = 0; j < 32; ++j) {
      float p[4], v[4];
#pragma unroll
      for (int r = 0; r < 4; ++r) p[r] = Ss[4 * ty + r][j];
#pragma unroll
      for (int dd = 0; dd < 4; ++dd) v[dd] = Vs[j][4 * tx + dd];
#pragma unroll
      for (int r = 0; r < 4; ++r)
#pragma unroll
        for (int dd = 0; dd < 4; ++dd)
          O[r][dd] = fmaf(p[r], v[dd], O[r][dd]);
    }
  }

  // epilogue: normalize and write model-layout attention output
#pragma unroll
  for (int r = 0; r < 4; ++r) {
    const int i = qb * 64 + 4 * ty + r;
    const float inv = 1.0f / lS[4 * ty + r];
#pragma unroll
    for (int dd = 0; dd < 4; ++dd)
      Om[(size_t)i * DMODEL + h * DHEAD + 4 * tx + dd] = O[r][dd] * inv;
  }
}

extern "C" void kernel_launch(void* const* d_in, const int* in_sizes, int n_in,
                              void* d_out, int out_size, void* d_ws, size_t ws_size,
                              hipStream_t stream) {
  const float* x  = (const float*)d_in[0];
  // d_in[1] = mask (causal tril, known analytically -> ignored)
  const float* Wq = (const float*)d_in[2];
  const float* Wk = (const float*)d_in[3];
  const float* Wv = (const float*)d_in[4];
  const float* Wo = (const float*)d_in[5];
  float* out = (float*)d_out;

  float* ws = (float*)d_ws;
  const size_t NELEM = (size_t)LSEQ * DMODEL;  // 4M floats
  float* Qh = ws;              // [H][L][DH]
  float* Kh = ws + NELEM;      // [H][L][DH]
  float* Vh = ws + 2 * NELEM;  // [H][L][DH]
  float* Om = ws + 3 * NELEM;  // [L][D] model layout

  dim3 gg(LSEQ / 64, DMODEL / 64), bb(256);
  gemm_nt<1><<<gg, bb, 0, stream>>>(x, Wq, Qh);
  gemm_nt<1><<<gg, bb, 0, stream>>>(x, Wk, Kh);
  gemm_nt<2><<<gg, bb, 0, stream>>>(x, Wv, Vh);
  attn_flash<<<dim3(NH, LSEQ / 64), bb, 0, stream>>>(Qh, Kh, Vh, Om);
  gemm_nt<0><<<gg, bb, 0, stream>>>(Om, Wo, out);
}

// Round 2
// 977.170 us; speedup vs baseline: 1.9942x; 1.9942x over previous
//
#include <hip/hip_runtime.h>
#include <math.h>

#define LSEQ   4096
#define DMODEL 1024
#define NH     16
#define DHEAD  64

typedef __attribute__((ext_vector_type(8))) short  bf16x8;
typedef __attribute__((ext_vector_type(4))) float  floatx4;
typedef unsigned short ushort_t;

__device__ __forceinline__ ushort_t f2bf(float x) {
  unsigned u = __builtin_bit_cast(unsigned, x);
  return (ushort_t)((u + 0x7fff + ((u >> 16) & 1)) >> 16);
}
__device__ __forceinline__ unsigned bf16pair(float a, float b) {
  return (unsigned)f2bf(a) | ((unsigned)f2bf(b) << 16);
}

// ---------------------------------------------------------------------------
// NT GEMM (fp32 compute): C[i][j] = sum_k A[i][k]*B[j][k]. 64x64 tile, BK=16.
// MODE 0: fp32 row-major out (final projection)
// MODE 1: RoPE epilogue -> bf16 head layout out[h][i][t]      (Q, K)
// MODE 2: bf16 TRANSPOSED head layout out[h][d][i] (= V^T)    (V)
// ---------------------------------------------------------------------------
template<int MODE>
__global__ __launch_bounds__(256)
void gemm_nt(const float* __restrict__ A, const float* __restrict__ B,
             void* __restrict__ Cv) {
  __shared__ float As[64][17];
  __shared__ float Bs[64][17];
  const int i0  = blockIdx.x * 64;
  const int j0  = blockIdx.y * 64;
  const int tid = threadIdx.x;
  const int tx  = tid & 15, ty = tid >> 4;
  const int lr  = tid >> 2;
  const int lk  = (tid & 3) << 2;

  float acc[4][4] = {};

  for (int k0 = 0; k0 < DMODEL; k0 += 16) {
    const float4 av = *(const float4*)(A + (size_t)(i0 + lr) * DMODEL + k0 + lk);
    const float4 bv = *(const float4*)(B + (size_t)(j0 + lr) * DMODEL + k0 + lk);
    As[lr][lk + 0] = av.x; As[lr][lk + 1] = av.y;
    As[lr][lk + 2] = av.z; As[lr][lk + 3] = av.w;
    Bs[lr][lk + 0] = bv.x; Bs[lr][lk + 1] = bv.y;
    Bs[lr][lk + 2] = bv.z; Bs[lr][lk + 3] = bv.w;
    __syncthreads();
#pragma unroll
    for (int k = 0; k < 16; ++k) {
      float a[4], b[4];
#pragma unroll
      for (int r = 0; r < 4; ++r) a[r] = As[4 * ty + r][k];
#pragma unroll
      for (int c = 0; c < 4; ++c) b[c] = Bs[4 * tx + c][k];
#pragma unroll
      for (int r = 0; r < 4; ++r)
#pragma unroll
        for (int c = 0; c < 4; ++c)
          acc[r][c] = fmaf(a[r], b[c], acc[r][c]);
    }
    __syncthreads();
  }

  if (MODE == 0) {
    float* C = (float*)Cv;
#pragma unroll
    for (int r = 0; r < 4; ++r) {
      const int i = i0 + 4 * ty + r;
#pragma unroll
      for (int c = 0; c < 4; ++c)
        C[(size_t)i * DMODEL + j0 + 4 * tx + c] = acc[r][c];
    }
  } else if (MODE == 2) {
    ushort_t* C = (ushort_t*)Cv;
    const int h = j0 >> 6;
#pragma unroll
    for (int r = 0; r < 4; ++r) {
      const int i = i0 + 4 * ty + r;
#pragma unroll
      for (int c = 0; c < 4; ++c)
        C[((size_t)(h * DHEAD + 4 * tx + c)) * LSEQ + i] = f2bf(acc[r][c]);
    }
  } else {
    ushort_t* C = (ushort_t*)Cv;
    const int h = j0 >> 6;
#pragma unroll
    for (int p = 0; p < 2; ++p) {
      const int t = 2 * tx + p;
      const double invf = exp((double)t * -0.28782313662425572);  // -ln(10000)/32
#pragma unroll
      for (int r = 0; r < 4; ++r) {
        const int i = i0 + 4 * ty + r;
        const float ang = (float)((double)i * invf);
        const float cs = cosf(ang), sn = sinf(ang);
        const float x1 = acc[r][2 * p], x2 = acc[r][2 * p + 1];
        ushort_t* base = C + ((size_t)h * LSEQ + i) * DHEAD;
        base[t]      = f2bf(x1 * cs - x2 * sn);
        base[t + 32] = f2bf(x1 * sn + x2 * cs);
      }
    }
  }
}

// ---------------------------------------------------------------------------
// MFMA flash attention, S^T formulation, barrier-free.
// Block: head h x 128 q-rows (paired: qb=yy then 31-yy). 4 waves x 32 q.
// Per 64-key tile, per wave:
//   S^T[key][q] = K . Q^T  (A=K frags, B=Q frags)  -> C layout: col=q, row=key
//   softmax per q-column: in-lane over 16 key-regs + shfl_xor(16,32)
//   P^T packed bf16 -> per-wave LDS (b64 writes) -> P B-frags (b128 reads)
//   O^T[d][q] += V^T . P^T  (A=Vt frags from global, B=P frags)
// ---------------------------------------------------------------------------
__global__ __launch_bounds__(256, 1)
void attn_mfma(const ushort_t* __restrict__ Qh, const ushort_t* __restrict__ Kh,
               const ushort_t* __restrict__ Vt, float* __restrict__ Om) {
  const int h   = blockIdx.x;
  const int yy  = blockIdx.y;
  const int tid = threadIdx.x;
  const int w    = tid >> 6;
  const int lane = tid & 63;
  const int quad = lane >> 4;
  const int col  = lane & 15;

  __shared__ ushort_t Ps[4][32 * 72];  // per-wave P^T buffer, pad 72 (bf16)
  ushort_t* psw = &Ps[w][0];

  for (int pass = 0; pass < 2; ++pass) {
    const int qb    = pass ? (31 - yy) : yy;
    const int qbase = qb * 128 + w * 32;

    // Q B-frags: B[n=q][k=dh], resident whole key loop
    bf16x8 qf[2][2];
#pragma unroll
    for (int nq = 0; nq < 2; ++nq)
#pragma unroll
      for (int c = 0; c < 2; ++c)
        qf[nq][c] = *(const bf16x8*)(Qh +
            ((size_t)(h * LSEQ + qbase + nq * 16 + col)) * DHEAD + quad * 8 + c * 32);

    floatx4 ot[4][2];
#pragma unroll
    for (int md = 0; md < 4; ++md)
#pragma unroll
      for (int nq = 0; nq < 2; ++nq) ot[md][nq] = (floatx4){0.f, 0.f, 0.f, 0.f};
    float m_[2] = {-1e30f, -1e30f}, l_[2] = {0.f, 0.f};

    const int nkt = 2 * qb + 1 + (w >> 1);  // waves 0,1 skip fully-masked tile
    for (int kt = 0; kt < nkt; ++kt) {
      const int key0 = kt * 64;

      bf16x8 kf[4][2], vf[4][2];
#pragma unroll
      for (int mk = 0; mk < 4; ++mk)
#pragma unroll
        for (int c = 0; c < 2; ++c)
          kf[mk][c] = *(const bf16x8*)(Kh +
              ((size_t)(h * LSEQ + key0 + mk * 16 + col)) * DHEAD + quad * 8 + c * 32);
#pragma unroll
      for (int md = 0; md < 4; ++md)
#pragma unroll
        for (int c = 0; c < 2; ++c)
          vf[md][c] = *(const bf16x8*)(Vt +
              ((size_t)(h * DHEAD + md * 16 + col)) * LSEQ + key0 + quad * 8 + c * 32);

      // S^T = K . Q^T
      floatx4 st[4][2];
#pragma unroll
      for (int mk = 0; mk < 4; ++mk)
#pragma unroll
        for (int nq = 0; nq < 2; ++nq) st[mk][nq] = (floatx4){0.f, 0.f, 0.f, 0.f};
#pragma unroll
      for (int mk = 0; mk < 4; ++mk)
#pragma unroll
        for (int c = 0; c < 2; ++c)
#pragma unroll
          for (int nq = 0; nq < 2; ++nq)
            st[mk][nq] = __builtin_amdgcn_mfma_f32_16x16x32_bf16(
                kf[mk][c], qf[nq][c], st[mk][nq], 0, 0, 0);

      // causal mask (only the wave's last tile can cross the diagonal)
      if (kt == nkt - 1) {
#pragma unroll
        for (int mk = 0; mk < 4; ++mk) {
          const int keyb = key0 + mk * 16 + quad * 4;
#pragma unroll
          for (int nq = 0; nq < 2; ++nq) {
            const int q = qbase + nq * 16 + col;
#pragma unroll
            for (int r = 0; r < 4; ++r)
              if (keyb + r > q) st[mk][nq][r] = -1e30f;
          }
        }
      }

      // online softmax per q-column (lane-local + 2 shfl)
      float alpha[2];
#pragma unroll
      for (int nq = 0; nq < 2; ++nq) {
        float rmax = -1e30f;
#pragma unroll
        for (int mk = 0; mk < 4; ++mk)
#pragma unroll
          for (int r = 0; r < 4; ++r) rmax = fmaxf(rmax, st[mk][nq][r]);
        rmax = fmaxf(rmax, __shfl_xor(rmax, 16));
        rmax = fmaxf(rmax, __shfl_xor(rmax, 32));
        const float mn = fmaxf(m_[nq], rmax * 0.125f);
        alpha[nq] = __expf(m_[nq] - mn);
        m_[nq]    = mn;
        float ls = 0.f;
#pragma unroll
        for (int mk = 0; mk < 4; ++mk)
#pragma unroll
          for (int r = 0; r < 4; ++r) {
            const float p = __expf(fmaf(st[mk][nq][r], 0.125f, -mn));
            st[mk][nq][r] = p;
            ls += p;
          }
        ls += __shfl_xor(ls, 16);
        ls += __shfl_xor(ls, 32);
        l_[nq] = l_[nq] * alpha[nq] + ls;
      }

      // P^T -> per-wave LDS (packed pairs: regs are consecutive keys)
#pragma unroll
      for (int mk = 0; mk < 4; ++mk)
#pragma unroll
        for (int nq = 0; nq < 2; ++nq) {
          uint2 pk;
          pk.x = bf16pair(st[mk][nq][0], st[mk][nq][1]);
          pk.y = bf16pair(st[mk][nq][2], st[mk][nq][3]);
          *(uint2*)(psw + (nq * 16 + col) * 72 + mk * 16 + quad * 4) = pk;
        }

      // P B-frags: B[n=q][k=key]
      bf16x8 pf[2][2];
#pragma unroll
      for (int nq = 0; nq < 2; ++nq)
#pragma unroll
        for (int c = 0; c < 2; ++c)
          pf[nq][c] = *(const bf16x8*)(psw + (nq * 16 + col) * 72 + c * 32 + quad * 8);

      // rescale O^T, then O^T += V^T . P^T
#pragma unroll
      for (int md = 0; md < 4; ++md)
#pragma unroll
        for (int nq = 0; nq < 2; ++nq)
#pragma unroll
          for (int r = 0; r < 4; ++r) ot[md][nq][r] *= alpha[nq];
#pragma unroll
      for (int md = 0; md < 4; ++md)
#pragma unroll
        for (int c = 0; c < 2; ++c)
#pragma unroll
          for (int nq = 0; nq < 2; ++nq)
            ot[md][nq] = __builtin_amdgcn_mfma_f32_16x16x32_bf16(
                vf[md][c], pf[nq][c], ot[md][nq], 0, 0, 0);
    }

    // epilogue: Om[q][h*64+d] = O^T[d][q] / l[q]   (scattered fp32; GEMM-friendly layout)
#pragma unroll
    for (int nq = 0; nq < 2; ++nq) {
      const float inv = 1.0f / l_[nq];
      const int q = qbase + nq * 16 + col;
#pragma unroll
      for (int md = 0; md < 4; ++md)
#pragma unroll
        for (int r = 0; r < 4; ++r)
          Om[(size_t)q * DMODEL + h * DHEAD + md * 16 + quad * 4 + r] =
              ot[md][nq][r] * inv;
    }
  }
}

extern "C" void kernel_launch(void* const* d_in, const int* in_sizes, int n_in,
                              void* d_out, int out_size, void* d_ws, size_t ws_size,
                              hipStream_t stream) {
  const float* x  = (const float*)d_in[0];
  const float* Wq = (const float*)d_in[2];
  const float* Wk = (const float*)d_in[3];
  const float* Wv = (const float*)d_in[4];
  const float* Wo = (const float*)d_in[5];
  float* out = (float*)d_out;

  const size_t NE = (size_t)NH * LSEQ * DHEAD;  // 4M elems
  ushort_t* Qh = (ushort_t*)d_ws;               // bf16 [H][L][DH]   8 MB
  ushort_t* Kh = Qh + NE;                       // bf16 [H][L][DH]   8 MB
  ushort_t* Vt = Kh + NE;                       // bf16 [H][DH][L]   8 MB
  float*    Om = (float*)(Vt + NE);             // fp32 [L][D]      16 MB

  dim3 gg(LSEQ / 64, DMODEL / 64), bb(256);
  gemm_nt<1><<<gg, bb, 0, stream>>>(x, Wq, Qh);
  gemm_nt<1><<<gg, bb, 0, stream>>>(x, Wk, Kh);
  gemm_nt<2><<<gg, bb, 0, stream>>>(x, Wv, Vt);
  attn_mfma<<<dim3(NH, 16), bb, 0, stream>>>(Qh, Kh, Vt, Om);
  gemm_nt<0><<<gg, bb, 0, stream>>>(Om, Wo, out);
}

// Round 3
// 346.297 us; speedup vs baseline: 5.6271x; 2.8218x over previous
//
#include <hip/hip_runtime.h>
#include <math.h>

#define LSEQ   4096
#define DMODEL 1024
#define NH     16
#define DHEAD  64

typedef __attribute__((ext_vector_type(8))) short  bf16x8;
typedef __attribute__((ext_vector_type(4))) float  floatx4;
typedef unsigned short ushort_t;

__device__ __forceinline__ ushort_t f2bf(float x) {
  unsigned u = __builtin_bit_cast(unsigned, x);
  return (ushort_t)((u + 0x7fff + ((u >> 16) & 1)) >> 16);
}
__device__ __forceinline__ unsigned bf16pair(float a, float b) {
  return (unsigned)f2bf(a) | ((unsigned)f2bf(b) << 16);
}
__device__ __forceinline__ void gl_lds16(const ushort_t* g, ushort_t* l) {
  __builtin_amdgcn_global_load_lds(
      (const __attribute__((address_space(1))) void*)g,
      (__attribute__((address_space(3))) void*)l, 16, 0, 0);
}

// ---------------------------------------------------------------------------
// Exact RoPE table: rope[s][t] = {cos(s*invf_t), sin(s*invf_t)}, 4096x32.
// ---------------------------------------------------------------------------
__global__ void rope_table(float2* __restrict__ rope) {
  const int idx = blockIdx.x * 256 + threadIdx.x;  // 131072 total
  const int s = idx >> 5, t = idx & 31;
  const double invf = exp((double)t * -0.28782313662425572);  // -ln(10000)/32
  const double ang = (double)s * invf;
  rope[idx] = make_float2((float)cos(ang), (float)sin(ang));
}

// ---------------------------------------------------------------------------
// fp32 -> bf16 for [x | Wq | Wk | Wv | Wo] into one contiguous buffer.
// ---------------------------------------------------------------------------
__global__ void cvt_bf16(const float* __restrict__ x,  const float* __restrict__ wq,
                         const float* __restrict__ wk, const float* __restrict__ wv,
                         const float* __restrict__ wo, ushort_t* __restrict__ dst) {
  const size_t e = ((size_t)blockIdx.x * 256 + threadIdx.x) * 4;  // elem idx, 8M total
  const float* src; size_t off;
  if      (e < (size_t)(4u << 20)) { src = x;  off = e; }
  else if (e < (size_t)(5u << 20)) { src = wq; off = e - (size_t)(4u << 20); }
  else if (e < (size_t)(6u << 20)) { src = wk; off = e - (size_t)(5u << 20); }
  else if (e < (size_t)(7u << 20)) { src = wv; off = e - (size_t)(6u << 20); }
  else                             { src = wo; off = e - (size_t)(7u << 20); }
  const float4 v = *(const float4*)(src + off);
  uint2 p; p.x = bf16pair(v.x, v.y); p.y = bf16pair(v.z, v.w);
  *(uint2*)(dst + e) = p;
}

// ---------------------------------------------------------------------------
// m97-style bf16 MFMA GEMM: C[m][n] = sum_k A[m][k]*B[n][k], K=1024, BK=64,
// 128x128 tile, 256 thr = 4 waves (2x2), each wave 4x4 of 16x16x32 frags,
// global_load_lds width-16 staging into unpadded LDS.
// MODE 0: A=Om(bf16), B=Wo(bf16) -> fp32 C row-major (final projection)
// MODE 1: A=W fused QKV rows (3072xK), B=x. m-dim = feature. Epilogues:
//         f<2048: RoPE -> Qh/Kh bf16 [H][L][DH]; f>=2048: V^T bf16 [H][DH][L]
// ---------------------------------------------------------------------------
template<int MODE>
__global__ __launch_bounds__(256)
void mfma_gemm(const ushort_t* __restrict__ A, const ushort_t* __restrict__ B,
               float* __restrict__ C, const float2* __restrict__ rope,
               ushort_t* __restrict__ Qo, ushort_t* __restrict__ Ko,
               ushort_t* __restrict__ Vo) {
  __shared__ ushort_t As[128 * 64];
  __shared__ ushort_t Bs[128 * 64];
  const int tid  = threadIdx.x;
  const int w    = tid >> 6, lane = tid & 63;
  const int wm   = w >> 1,   wn   = w & 1;
  const int quad = lane >> 4, col = lane & 15;
  const int i0 = blockIdx.x * 128;  // A-row (m) tile base
  const int j0 = blockIdx.y * 128;  // B-row (n) tile base

  const ushort_t* Ab = A + (size_t)i0 * DMODEL;
  const ushort_t* Bb = B + (size_t)j0 * DMODEL;

  floatx4 acc[4][4];
#pragma unroll
  for (int mt = 0; mt < 4; ++mt)
#pragma unroll
    for (int nt = 0; nt < 4; ++nt) acc[mt][nt] = (floatx4){0.f, 0.f, 0.f, 0.f};

  const int lrow = lane >> 3;          // 0..7 within 8-row chunk
  const int lcol = (lane & 7) * 8;     // 8 bf16 = 16 B

  for (int k0 = 0; k0 < DMODEL; k0 += 64) {
    __syncthreads();  // previous tile's ds_reads complete
#pragma unroll
    for (int it = 0; it < 4; ++it) {
      const int rb = (it * 4 + w) * 8;  // wave-uniform 8-row chunk
      gl_lds16(Ab + (size_t)(rb + lrow) * DMODEL + k0 + lcol, As + rb * 64);
      gl_lds16(Bb + (size_t)(rb + lrow) * DMODEL + k0 + lcol, Bs + rb * 64);
    }
    __syncthreads();  // staging visible (vmcnt(0) drained by barrier)

#pragma unroll
    for (int kk = 0; kk < 64; kk += 32) {
      bf16x8 af[4], bfr[4];
#pragma unroll
      for (int mt = 0; mt < 4; ++mt)
        af[mt] = *(const bf16x8*)(As + (wm * 64 + mt * 16 + col) * 64 + kk + quad * 8);
#pragma unroll
      for (int nt = 0; nt < 4; ++nt)
        bfr[nt] = *(const bf16x8*)(Bs + (wn * 64 + nt * 16 + col) * 64 + kk + quad * 8);
#pragma unroll
      for (int mt = 0; mt < 4; ++mt)
#pragma unroll
        for (int nt = 0; nt < 4; ++nt)
          acc[mt][nt] = __builtin_amdgcn_mfma_f32_16x16x32_bf16(
              af[mt], bfr[nt], acc[mt][nt], 0, 0, 0);
    }
  }

  if (MODE == 0) {
#pragma unroll
    for (int mt = 0; mt < 4; ++mt) {
      const int i = i0 + wm * 64 + mt * 16 + quad * 4;
#pragma unroll
      for (int nt = 0; nt < 4; ++nt) {
        const int j = j0 + wn * 64 + nt * 16 + col;
#pragma unroll
        for (int r = 0; r < 4; ++r)
          C[(size_t)(i + r) * DMODEL + j] = acc[mt][nt][r];
      }
    }
  } else {
    const int which = i0 >> 10;               // 0=Q 1=K 2=V (uniform per block)
#pragma unroll
    for (int mt = 0; mt < 4; ++mt) {
      const int f0 = i0 + wm * 64 + mt * 16 + quad * 4;
      const int h  = (f0 >> 6) & 15;
      const int d  = f0 & 63;                 // multiple of 4
      if (which == 2) {
#pragma unroll
        for (int nt = 0; nt < 4; ++nt) {
          const int s = j0 + wn * 64 + nt * 16 + col;
#pragma unroll
          for (int r = 0; r < 4; ++r)
            Vo[(size_t)(h * DHEAD + d + r) * LSEQ + s] = f2bf(acc[mt][nt][r]);
        }
      } else {
        ushort_t* dst = which ? Ko : Qo;
        const int t0 = d >> 1;                // even
#pragma unroll
        for (int nt = 0; nt < 4; ++nt) {
          const int s = j0 + wn * 64 + nt * 16 + col;
          const float4 cst = *(const float4*)((const float*)rope + ((size_t)s << 6) + t0 * 2);
          ushort_t* ob = dst + ((size_t)h * LSEQ + s) * DHEAD;
          const float x1 = acc[mt][nt][0], x2 = acc[mt][nt][1];
          const float y1 = acc[mt][nt][2], y2 = acc[mt][nt][3];
          *(unsigned*)(ob + t0)      = bf16pair(x1 * cst.x - x2 * cst.y,
                                                y1 * cst.z - y2 * cst.w);
          *(unsigned*)(ob + t0 + 32) = bf16pair(x1 * cst.y + x2 * cst.x,
                                                y1 * cst.w + y2 * cst.z);
        }
      }
    }
  }
}

// ---------------------------------------------------------------------------
// MFMA flash attention (unchanged structure from R2); epilogue now bf16 Om.
// ---------------------------------------------------------------------------
__global__ __launch_bounds__(256, 1)
void attn_mfma(const ushort_t* __restrict__ Qh, const ushort_t* __restrict__ Kh,
               const ushort_t* __restrict__ Vt, ushort_t* __restrict__ Om) {
  const int h   = blockIdx.x;
  const int yy  = blockIdx.y;
  const int tid = threadIdx.x;
  const int w    = tid >> 6;
  const int lane = tid & 63;
  const int quad = lane >> 4;
  const int col  = lane & 15;

  __shared__ ushort_t Ps[4][32 * 72];
  ushort_t* psw = &Ps[w][0];

  for (int pass = 0; pass < 2; ++pass) {
    const int qb    = pass ? (31 - yy) : yy;
    const int qbase = qb * 128 + w * 32;

    bf16x8 qf[2][2];
#pragma unroll
    for (int nq = 0; nq < 2; ++nq)
#pragma unroll
      for (int c = 0; c < 2; ++c)
        qf[nq][c] = *(const bf16x8*)(Qh +
            ((size_t)(h * LSEQ + qbase + nq * 16 + col)) * DHEAD + quad * 8 + c * 32);

    floatx4 ot[4][2];
#pragma unroll
    for (int md = 0; md < 4; ++md)
#pragma unroll
      for (int nq = 0; nq < 2; ++nq) ot[md][nq] = (floatx4){0.f, 0.f, 0.f, 0.f};
    float m_[2] = {-1e30f, -1e30f}, l_[2] = {0.f, 0.f};

    const int nkt = 2 * qb + 1 + (w >> 1);
    for (int kt = 0; kt < nkt; ++kt) {
      const int key0 = kt * 64;

      bf16x8 kf[4][2], vf[4][2];
#pragma unroll
      for (int mk = 0; mk < 4; ++mk)
#pragma unroll
        for (int c = 0; c < 2; ++c)
          kf[mk][c] = *(const bf16x8*)(Kh +
              ((size_t)(h * LSEQ + key0 + mk * 16 + col)) * DHEAD + quad * 8 + c * 32);
#pragma unroll
      for (int md = 0; md < 4; ++md)
#pragma unroll
        for (int c = 0; c < 2; ++c)
          vf[md][c] = *(const bf16x8*)(Vt +
              ((size_t)(h * DHEAD + md * 16 + col)) * LSEQ + key0 + quad * 8 + c * 32);

      floatx4 st[4][2];
#pragma unroll
      for (int mk = 0; mk < 4; ++mk)
#pragma unroll
        for (int nq = 0; nq < 2; ++nq) st[mk][nq] = (floatx4){0.f, 0.f, 0.f, 0.f};
#pragma unroll
      for (int mk = 0; mk < 4; ++mk)
#pragma unroll
        for (int c = 0; c < 2; ++c)
#pragma unroll
          for (int nq = 0; nq < 2; ++nq)
            st[mk][nq] = __builtin_amdgcn_mfma_f32_16x16x32_bf16(
                kf[mk][c], qf[nq][c], st[mk][nq], 0, 0, 0);

      if (kt == nkt - 1) {
#pragma unroll
        for (int mk = 0; mk < 4; ++mk) {
          const int keyb = key0 + mk * 16 + quad * 4;
#pragma unroll
          for (int nq = 0; nq < 2; ++nq) {
            const int q = qbase + nq * 16 + col;
#pragma unroll
            for (int r = 0; r < 4; ++r)
              if (keyb + r > q) st[mk][nq][r] = -1e30f;
          }
        }
      }

      float alpha[2];
#pragma unroll
      for (int nq = 0; nq < 2; ++nq) {
        float rmax = -1e30f;
#pragma unroll
        for (int mk = 0; mk < 4; ++mk)
#pragma unroll
          for (int r = 0; r < 4; ++r) rmax = fmaxf(rmax, st[mk][nq][r]);
        rmax = fmaxf(rmax, __shfl_xor(rmax, 16));
        rmax = fmaxf(rmax, __shfl_xor(rmax, 32));
        const float mn = fmaxf(m_[nq], rmax * 0.125f);
        alpha[nq] = __expf(m_[nq] - mn);
        m_[nq]    = mn;
        float ls = 0.f;
#pragma unroll
        for (int mk = 0; mk < 4; ++mk)
#pragma unroll
          for (int r = 0; r < 4; ++r) {
            const float p = __expf(fmaf(st[mk][nq][r], 0.125f, -mn));
            st[mk][nq][r] = p;
            ls += p;
          }
        ls += __shfl_xor(ls, 16);
        ls += __shfl_xor(ls, 32);
        l_[nq] = l_[nq] * alpha[nq] + ls;
      }

#pragma unroll
      for (int mk = 0; mk < 4; ++mk)
#pragma unroll
        for (int nq = 0; nq < 2; ++nq) {
          uint2 pk;
          pk.x = bf16pair(st[mk][nq][0], st[mk][nq][1]);
          pk.y = bf16pair(st[mk][nq][2], st[mk][nq][3]);
          *(uint2*)(psw + (nq * 16 + col) * 72 + mk * 16 + quad * 4) = pk;
        }

      bf16x8 pf[2][2];
#pragma unroll
      for (int nq = 0; nq < 2; ++nq)
#pragma unroll
        for (int c = 0; c < 2; ++c)
          pf[nq][c] = *(const bf16x8*)(psw + (nq * 16 + col) * 72 + c * 32 + quad * 8);

#pragma unroll
      for (int md = 0; md < 4; ++md)
#pragma unroll
        for (int nq = 0; nq < 2; ++nq)
#pragma unroll
          for (int r = 0; r < 4; ++r) ot[md][nq][r] *= alpha[nq];
#pragma unroll
      for (int md = 0; md < 4; ++md)
#pragma unroll
        for (int c = 0; c < 2; ++c)
#pragma unroll
          for (int nq = 0; nq < 2; ++nq)
            ot[md][nq] = __builtin_amdgcn_mfma_f32_16x16x32_bf16(
                vf[md][c], pf[nq][c], ot[md][nq], 0, 0, 0);
    }

#pragma unroll
    for (int nq = 0; nq < 2; ++nq) {
      const float inv = 1.0f / l_[nq];
      const int q = qbase + nq * 16 + col;
#pragma unroll
      for (int md = 0; md < 4; ++md) {
        uint2 pk;
        pk.x = bf16pair(ot[md][nq][0] * inv, ot[md][nq][1] * inv);
        pk.y = bf16pair(ot[md][nq][2] * inv, ot[md][nq][3] * inv);
        *(uint2*)(Om + (size_t)q * DMODEL + h * DHEAD + md * 16 + quad * 4) = pk;
      }
    }
  }
}

extern "C" void kernel_launch(void* const* d_in, const int* in_sizes, int n_in,
                              void* d_out, int out_size, void* d_ws, size_t ws_size,
                              hipStream_t stream) {
  const float* x  = (const float*)d_in[0];
  const float* Wq = (const float*)d_in[2];
  const float* Wk = (const float*)d_in[3];
  const float* Wv = (const float*)d_in[4];
  const float* Wo = (const float*)d_in[5];
  float* out = (float*)d_out;

  const size_t M1 = (size_t)1 << 20;
  ushort_t* xb  = (ushort_t*)d_ws;      // bf16 x          4M elems
  ushort_t* Wb  = xb  + 4 * M1;         // bf16 Wq|Wk|Wv   3M (contiguous)
  ushort_t* wob = Wb  + 3 * M1;         // bf16 Wo         1M
  ushort_t* Qh  = wob + 1 * M1;         // bf16 [H][L][DH] 4M
  ushort_t* Kh  = Qh  + 4 * M1;         // bf16 [H][L][DH] 4M
  ushort_t* Vt  = Kh  + 4 * M1;         // bf16 [H][DH][L] 4M
  ushort_t* Om  = Vt  + 4 * M1;         // bf16 [L][D]     4M
  float2*   rope = (float2*)(Om + 4 * M1);  // 4096x32 float2, 1 MB

  rope_table<<<512, 256, 0, stream>>>(rope);
  cvt_bf16<<<8192, 256, 0, stream>>>(x, Wq, Wk, Wv, Wo, xb);
  // fused QKV, transposed orientation: m = feature (3072), n = seq (4096)
  mfma_gemm<1><<<dim3(3072 / 128, LSEQ / 128), 256, 0, stream>>>(
      Wb, xb, nullptr, rope, Qh, Kh, Vt);
  attn_mfma<<<dim3(NH, 16), 256, 0, stream>>>(Qh, Kh, Vt, Om);
  // final projection: m = seq, n = feature
  mfma_gemm<0><<<dim3(LSEQ / 128, DMODEL / 128), 256, 0, stream>>>(
      Om, wob, out, nullptr, nullptr, nullptr, nullptr);
}